// Round 4
// baseline (274.438 us; speedup 1.0000x reference)
//
#include <hip/hip_runtime.h>
#include <hip/hip_bf16.h>
#include <cstdint>

typedef __attribute__((ext_vector_type(8))) short sh8;
typedef __attribute__((ext_vector_type(16))) float f32x16;
typedef unsigned short ushort_t;

#define HH 128
#define WW 128
#define HWSZ (HH*WW)
#define PW 130
#define PW64 (PW*64)
#define IMGSZ ((size_t)PW*PW*64)   // padded NHWC image, elements
#define WBEXP 36864                // elems per packed weight set: 9*4*2*512

__device__ __forceinline__ float gelu_tanh(float x) {
    float u = 0.7978845608028654f * (x + 0.044715f * x * x * x);
    return 0.5f * x * (1.0f + tanhf(u));
}
__device__ __forceinline__ ushort_t f2b(float f) {
    __hip_bfloat16 h = __float2bfloat16(f);
    return *reinterpret_cast<ushort_t*>(&h);
}
__device__ __forceinline__ f32x16 mfma_bf16(sh8 a, sh8 b, f32x16 c) {
    return __builtin_amdgcn_mfma_f32_32x32x16_bf16(a, b, c, 0, 0, 0);
}

// ---------------- router (+bsum, +tuple-tail zero); pooled holds SUMS ----------
__global__ __launch_bounds__(64) void router_kernel(const float* __restrict__ pooled,
                                                    const float* __restrict__ rw,
                                                    const float* __restrict__ rb,
                                                    const float* __restrict__ eb,
                                                    const float* __restrict__ b2,
                                                    int* __restrict__ topi,
                                                    float* __restrict__ topw,
                                                    float* __restrict__ bsum,
                                                    float* __restrict__ outz) {
    __shared__ int sti[16];
    __shared__ float stw[16];
    int b = threadIdx.x;
    if (b == 8) outz[(size_t)8 * 64 * HWSZ] = 0.f;  // tuple's scalar 0
    if (b < 8) {
        float lg[6];
        for (int e = 0; e < 6; ++e) {
            float s = 0.f;
            for (int c = 0; c < 64; ++c) s += pooled[b * 64 + c] * rw[e * 64 + c];
            s = s * (1.0f / (float)HWSZ) + rb[e];
            lg[e] = fminf(fmaxf(s, -10.f), 10.f) + eb[e];
        }
        float m = lg[0];
        for (int e = 1; e < 6; ++e) m = fmaxf(m, lg[e]);
        float den = 0.f, pr[6];
        for (int e = 0; e < 6; ++e) { pr[e] = expf(lg[e] - m); den += pr[e]; }
        float inv = 1.0f / den;
        for (int e = 0; e < 6; ++e) pr[e] = fminf(fmaxf(pr[e] * inv, 1e-6f), 1.0f);
        int i0 = 0; float v0 = pr[0];
        for (int e = 1; e < 6; ++e) if (pr[e] > v0) { v0 = pr[e]; i0 = e; }
        int i1 = -1; float v1 = -1.f;
        for (int e = 0; e < 6; ++e) { if (e == i0) continue; if (pr[e] > v1) { v1 = pr[e]; i1 = e; } }
        float s2 = v0 + v1 + 1e-8f;
        topi[b * 2 + 0] = i0; topi[b * 2 + 1] = i1;
        topw[b * 2 + 0] = v0 / s2; topw[b * 2 + 1] = v1 / s2;
        sti[b * 2 + 0] = i0; sti[b * 2 + 1] = i1;
        stw[b * 2 + 0] = v0 / s2; stw[b * 2 + 1] = v1 / s2;
    }
    __syncthreads();
    for (int i = threadIdx.x; i < 512; i += 64) {
        int bb = i >> 6, c = i & 63;
        bsum[i] = stw[bb * 2] * b2[sti[bb * 2] * 64 + c] +
                  stw[bb * 2 + 1] * b2[sti[bb * 2 + 1] * 64 + c];
    }
}

// ------------- x: NCHW fp32 -> padded NHWC bf16, fused global-avg-pool ---------
__global__ __launch_bounds__(256) void convx_kernel(const float* __restrict__ x,
                                                    ushort_t* __restrict__ xp,
                                                    float* __restrict__ pooled) {
    __shared__ ushort_t lt[128][72];
    int b = blockIdx.x >> 7, h = blockIdx.x & 127;
    int tid = threadIdx.x;
#pragma unroll
    for (int k = 0; k < 8; ++k) {
        int idx = tid + k * 256;            // 0..2047
        int ci = idx >> 5, wg = idx & 31;
        float4 v = *reinterpret_cast<const float4*>(
            x + ((size_t)b * 64 + ci) * HWSZ + (size_t)h * WW + wg * 4);
        lt[wg * 4 + 0][ci] = f2b(v.x);
        lt[wg * 4 + 1][ci] = f2b(v.y);
        lt[wg * 4 + 2][ci] = f2b(v.z);
        lt[wg * 4 + 3][ci] = f2b(v.w);
        // fused pool partial: reduce row-sum for this ci over the 32-lane group
        float s4 = (v.x + v.y) + (v.z + v.w);
#pragma unroll
        for (int m = 16; m > 0; m >>= 1) s4 += __shfl_xor(s4, m, 64);
        if ((tid & 31) == 0) atomicAdd(pooled + b * 64 + ci, s4);
    }
    __syncthreads();
    int w = tid >> 1, half = tid & 1;
    const int4* src = reinterpret_cast<const int4*>(&lt[w][half * 32]);
    int4 a0 = src[0], a1 = src[1], a2 = src[2], a3 = src[3];
    int4* dst = reinterpret_cast<int4*>(
        xp + (((size_t)b * PW + (h + 1)) * PW + (w + 1)) * 64 + half * 32);
    dst[0] = a0; dst[1] = a1; dst[2] = a2; dst[3] = a3;
}

// ------------- w1 -> fragment-linear bf16: [e][t][kc][n][lane][8] -------------
__global__ __launch_bounds__(256) void convw1_kernel(const float* __restrict__ w1,
                                                     ushort_t* __restrict__ wb1f) {
    int blk = blockIdx.x;          // e*9+t, 54 blocks
    int e = blk / 9, t = blk - e * 9;
    for (int idx = threadIdx.x; idx < 4096; idx += 256) {
        int kc = idx >> 10, n = (idx >> 9) & 1, l = (idx >> 3) & 63, j = idx & 7;
        int co = n * 32 + (l & 31);
        int ci = kc * 16 + (l >> 5) * 8 + j;
        wb1f[(size_t)e * WBEXP + t * 4096 + idx] =
            f2b(w1[(((size_t)e * 64 + co) * 64 + ci) * 9 + t]);
    }
}

// ------------- w2 -> cw-scaled fragment-linear bf16: [bs][t][kc][n][lane][8] ----
__global__ __launch_bounds__(256) void convw2_kernel(const float* __restrict__ w2,
                                                     const int* __restrict__ topi,
                                                     const float* __restrict__ topw,
                                                     ushort_t* __restrict__ wb2f) {
    int blk = blockIdx.x;          // bs*9+t, 144 blocks
    int bs = blk / 9, t = blk - bs * 9;
    int e = topi[bs];
    float cw = topw[bs];
    for (int idx = threadIdx.x; idx < 4096; idx += 256) {
        int kc = idx >> 10, n = (idx >> 9) & 1, l = (idx >> 3) & 63, j = idx & 7;
        int co = n * 32 + (l & 31);
        int ci = kc * 16 + (l >> 5) * 8 + j;
        wb2f[(size_t)bs * WBEXP + t * 4096 + idx] =
            f2b(cw * w2[(((size_t)e * 64 + co) * 64 + ci) * 9 + t]);
    }
}

// ------------- zero halos: images 0..7 = xp, 8.. = hp -------------
__global__ __launch_bounds__(256) void halo_kernel(ushort_t* __restrict__ xp,
                                                   ushort_t* __restrict__ hp) {
    int img = blockIdx.x;
    ushort_t* p = (img < 8) ? (xp + (size_t)img * IMGSZ) : (hp + (size_t)(img - 8) * IMGSZ);
    int tid = threadIdx.x;
    int4 z = make_int4(0, 0, 0, 0);
    for (int i = tid; i < 1040; i += 256) {          // top + bottom rows
        reinterpret_cast<int4*>(p)[i] = z;
        reinterpret_cast<int4*>(p + (size_t)129 * PW64)[i] = z;
    }
    for (int i = tid; i < 128 * 8; i += 256) {       // left + right cols
        int row = 1 + (i >> 3), j = i & 7;
        reinterpret_cast<int4*>(p + (size_t)row * PW64)[j] = z;
        reinterpret_cast<int4*>(p + ((size_t)row * PW + 129) * 64)[j] = z;
    }
}

// ------------- conv1: xp -> gelu(conv+b1) -> hp  (2 rows/wave, 4-deep pipeline) -
__global__ __launch_bounds__(256, 4) void conv1_mfma(const ushort_t* __restrict__ xp,
                                                     const ushort_t* __restrict__ wb1f,
                                                     const float* __restrict__ b1,
                                                     const int* __restrict__ topi,
                                                     ushort_t* __restrict__ hp,
                                                     int nslots, int slot0) {
    const int z = blockIdx.z;
    const int b = z / nslots, sl = z - b * nslots, s = slot0 + sl;
    const int e = topi[b * 2 + s];
    const int tid = threadIdx.x, l = tid & 63, wid = tid >> 6;
    const int n = wid & 1, rp = wid >> 1;
    const int hgrp = blockIdx.x >> 2, w0 = (blockIdx.x & 3) * 32;
    const int l31 = l & 31, lh = l >> 5;
    const int h0 = hgrp * 4 + rp * 2;   // 2 output rows h0, h0+1

    const ushort_t* aB = xp + (size_t)b * IMGSZ + (size_t)h0 * PW64 +
                         (size_t)w0 * 64 + l31 * 64 + lh * 8;
    const ushort_t* wB = wb1f + (size_t)e * WBEXP + n * 512 + l * 8;

    f32x16 acc0, acc1;
#pragma unroll
    for (int k2 = 0; k2 < 16; ++k2) { acc0[k2] = 0.f; acc1[k2] = 0.f; }

    sh8 bA0[4], bA1[4], bB[4];
#pragma unroll
    for (int it = 0; it < 3; ++it) {
        const int t = it >> 2, kc = it & 3, dr = t / 3, dc = t - dr * 3;
        const ushort_t* ap = aB + (size_t)dr * PW64 + dc * 64 + kc * 16;
        bA0[it] = *reinterpret_cast<const sh8*>(ap);
        bA1[it] = *reinterpret_cast<const sh8*>(ap + PW64);
        bB[it]  = *reinterpret_cast<const sh8*>(wB + t * 4096 + kc * 1024);
    }
#pragma unroll
    for (int it = 0; it < 36; ++it) {
        if (it + 3 < 36) {
            const int jt = it + 3;
            const int t = jt >> 2, kc = jt & 3, dr = t / 3, dc = t - dr * 3;
            const ushort_t* ap = aB + (size_t)dr * PW64 + dc * 64 + kc * 16;
            bA0[jt & 3] = *reinterpret_cast<const sh8*>(ap);
            bA1[jt & 3] = *reinterpret_cast<const sh8*>(ap + PW64);
            bB[jt & 3]  = *reinterpret_cast<const sh8*>(wB + t * 4096 + kc * 1024);
        }
        acc0 = mfma_bf16(bA0[it & 3], bB[it & 3], acc0);
        acc1 = mfma_bf16(bA1[it & 3], bB[it & 3], acc1);
    }

    const float bv = b1[e * 64 + n * 32 + l31];
    const size_t ob0 = (((size_t)(sl * 8 + b) * PW + (h0 + 1)) * PW + (w0 + 1)) * 64 + n * 32 + l31;
#pragma unroll
    for (int i = 0; i < 2; ++i) {
        f32x16 a = i ? acc1 : acc0;
        const size_t ob = ob0 + (size_t)i * PW64;
#pragma unroll
        for (int r = 0; r < 16; ++r) {
            int px = (r & 3) + 8 * (r >> 2) + 4 * lh;
            hp[ob + (size_t)px * 64] = f2b(gelu_tanh(a[r] + bv));
        }
    }
}

// ------------- conv2: hp(NS slots) -> sum conv (+bsum) -> out NCHW fp32 --------
template <int NS>
__global__ __launch_bounds__(256, 4) void conv2_mfma(const ushort_t* __restrict__ hp,
                                                     const ushort_t* __restrict__ wb2f,
                                                     const float* __restrict__ bsum,
                                                     float* __restrict__ outF,
                                                     int s0, int addmode) {
    __shared__ float lt[4][32][33];
    const int b = blockIdx.z;
    const int tid = threadIdx.x, l = tid & 63, wid = tid >> 6;
    const int n = wid & 1, rp = wid >> 1;
    const int hgrp = blockIdx.x >> 2, w0 = (blockIdx.x & 3) * 32;
    const int l31 = l & 31, lh = l >> 5;
    const int h0 = hgrp * 4 + rp * 2;   // 2 output rows

    const ushort_t* aB = hp + (size_t)b * IMGSZ + (size_t)h0 * PW64 +
                         (size_t)w0 * 64 + l31 * 64 + lh * 8;
    const ushort_t* wB = wb2f + (size_t)(b * 2 + s0) * WBEXP + n * 512 + l * 8;

    constexpr int NIT = NS * 36;
    f32x16 acc0, acc1;
#pragma unroll
    for (int k2 = 0; k2 < 16; ++k2) { acc0[k2] = 0.f; acc1[k2] = 0.f; }

    sh8 bA0[4], bA1[4], bB[4];
#pragma unroll
    for (int it = 0; it < 3; ++it) {
        const int si = it / 36, r = it - si * 36;
        const int t = r >> 2, kc = r & 3, dr = t / 3, dc = t - dr * 3;
        const ushort_t* ap = aB + (size_t)si * 8 * IMGSZ + (size_t)dr * PW64 + dc * 64 + kc * 16;
        bA0[it] = *reinterpret_cast<const sh8*>(ap);
        bA1[it] = *reinterpret_cast<const sh8*>(ap + PW64);
        bB[it]  = *reinterpret_cast<const sh8*>(wB + (size_t)si * WBEXP + t * 4096 + kc * 1024);
    }
#pragma unroll
    for (int it = 0; it < NIT; ++it) {
        if (it + 3 < NIT) {
            const int jt = it + 3;
            const int si = jt / 36, r = jt - si * 36;
            const int t = r >> 2, kc = r & 3, dr = t / 3, dc = t - dr * 3;
            const ushort_t* ap = aB + (size_t)si * 8 * IMGSZ + (size_t)dr * PW64 + dc * 64 + kc * 16;
            bA0[jt & 3] = *reinterpret_cast<const sh8*>(ap);
            bA1[jt & 3] = *reinterpret_cast<const sh8*>(ap + PW64);
            bB[jt & 3]  = *reinterpret_cast<const sh8*>(wB + (size_t)si * WBEXP + t * 4096 + kc * 1024);
        }
        acc0 = mfma_bf16(bA0[it & 3], bB[it & 3], acc0);
        acc1 = mfma_bf16(bA1[it & 3], bB[it & 3], acc1);
    }

    const float bq = addmode ? 0.f : bsum[b * 64 + n * 32 + l31];
#pragma unroll
    for (int i = 0; i < 2; ++i) {
        f32x16 a = i ? acc1 : acc0;
        const int h = h0 + i;
#pragma unroll
        for (int r = 0; r < 16; ++r) {
            int px = (r & 3) + 8 * (r >> 2) + 4 * lh;
            lt[wid][px][l31] = a[r] + bq;
        }
        const int q = lh, co = l31;
        const size_t ob = ((size_t)(b * 64 + n * 32 + co)) * HWSZ + (size_t)h * WW + w0 + q * 16;
#pragma unroll
        for (int v = 0; v < 4; ++v) {
            float o0 = lt[wid][q * 16 + v * 4 + 0][co];
            float o1 = lt[wid][q * 16 + v * 4 + 1][co];
            float o2 = lt[wid][q * 16 + v * 4 + 2][co];
            float o3 = lt[wid][q * 16 + v * 4 + 3][co];
            float4* dst = reinterpret_cast<float4*>(outF + ob + v * 4);
            if (addmode) {
                float4 pv = *dst;
                o0 += pv.x; o1 += pv.y; o2 += pv.z; o3 += pv.w;
            }
            float4 o; o.x = o0; o.y = o1; o.z = o2; o.w = o3;
            *dst = o;
        }
    }
}

extern "C" void kernel_launch(void* const* d_in, const int* in_sizes, int n_in,
                              void* d_out, int out_size, void* d_ws, size_t ws_size,
                              hipStream_t stream) {
    const float* x  = (const float*)d_in[0];
    const float* rw = (const float*)d_in[1];
    const float* rb = (const float*)d_in[2];
    const float* eb = (const float*)d_in[3];
    const float* w1 = (const float*)d_in[4];
    const float* b1 = (const float*)d_in[5];
    const float* w2 = (const float*)d_in[6];
    const float* b2 = (const float*)d_in[7];
    float* out = (float*)d_out;

    char* ws = (char*)d_ws;
    float*    pooled = (float*)(ws + 0);
    int*      topi   = (int*)(ws + 2048);
    float*    topw   = (float*)(ws + 2112);
    float*    bsum   = (float*)(ws + 2176);
    ushort_t* wb1f   = (ushort_t*)(ws + 4352);
    ushort_t* wb2f   = (ushort_t*)(ws + 446720);
    ushort_t* xp     = (ushort_t*)(ws + 1626368);
    ushort_t* hp     = (ushort_t*)(ws + 18931968);

    const bool two = ws_size >= 53543168ull;  // hp holds both slots?

    hipMemsetAsync(pooled, 0, 512 * sizeof(float), stream);
    hipLaunchKernelGGL(convx_kernel, dim3(1024), dim3(256), 0, stream, x, xp, pooled);
    hipLaunchKernelGGL(router_kernel, dim3(1), dim3(64), 0, stream,
                       pooled, rw, rb, eb, b2, topi, topw, bsum, out);
    hipLaunchKernelGGL(convw1_kernel, dim3(54), dim3(256), 0, stream, w1, wb1f);
    hipLaunchKernelGGL(convw2_kernel, dim3(144), dim3(256), 0, stream, w2, topi, topw, wb2f);
    hipLaunchKernelGGL(halo_kernel, dim3(two ? 24 : 16), dim3(256), 0, stream, xp, hp);

    if (two) {
        hipLaunchKernelGGL(conv1_mfma, dim3(128, 1, 16), dim3(256), 0, stream,
                           xp, wb1f, b1, topi, hp, 2, 0);
        hipLaunchKernelGGL((conv2_mfma<2>), dim3(128, 1, 8), dim3(256), 0, stream,
                           hp, wb2f, bsum, out, 0, 0);
    } else {
        hipLaunchKernelGGL(conv1_mfma, dim3(128, 1, 8), dim3(256), 0, stream,
                           xp, wb1f, b1, topi, hp, 1, 0);
        hipLaunchKernelGGL((conv2_mfma<1>), dim3(128, 1, 8), dim3(256), 0, stream,
                           hp, wb2f, bsum, out, 0, 0);
        hipLaunchKernelGGL(conv1_mfma, dim3(128, 1, 8), dim3(256), 0, stream,
                           xp, wb1f, b1, topi, hp, 1, 1);
        hipLaunchKernelGGL((conv2_mfma<1>), dim3(128, 1, 8), dim3(256), 0, stream,
                           hp, wb2f, bsum, out, 1, 1);
    }
}

// Round 5
// 251.718 us; speedup vs baseline: 1.0903x; 1.0903x over previous
//
#include <hip/hip_runtime.h>
#include <hip/hip_bf16.h>
#include <cstdint>

typedef __attribute__((ext_vector_type(8))) short sh8;
typedef __attribute__((ext_vector_type(16))) float f32x16;
typedef unsigned short ushort_t;

#define HH 128
#define WW 128
#define HWSZ (HH*WW)
#define PW 130
#define PW64 (PW*64)
#define IMGSZ ((size_t)PW*PW*64)   // padded NHWC image, elements
#define WBEXP 36864                // elems per packed weight set: 9*4*2*512

// conv tile: 8 output rows x 32 cols, staged input 10 x 34 x 64ci bf16 in LDS
#define TR 8
#define SROWS 10
#define SCOLS 34
#define ASTR (SCOLS*128)           // 4352 B per staged row
#define ACHUNKS (SROWS*SCOLS*8)    // 2720 16-byte chunks

__device__ __forceinline__ float gelu_tanh(float x) {
    float u = 0.7978845608028654f * (x + 0.044715f * x * x * x);
    return 0.5f * x * (1.0f + tanhf(u));
}
__device__ __forceinline__ ushort_t f2b(float f) {
    __hip_bfloat16 h = __float2bfloat16(f);
    return *reinterpret_cast<ushort_t*>(&h);
}
__device__ __forceinline__ f32x16 mfma_bf16(sh8 a, sh8 b, f32x16 c) {
    return __builtin_amdgcn_mfma_f32_32x32x16_bf16(a, b, c, 0, 0, 0);
}

// stage one padded-NHWC tile (rows h0..h0+9, cols w0..w0+33) into swizzled LDS.
// imgRow = image base pre-offset to (b, h0). Swizzle: byte ^= ((col&7)<<4).
__device__ __forceinline__ void stage_tile(const ushort_t* __restrict__ imgRow,
                                           char* smem, int w0, int tid) {
#pragma unroll
    for (int it = 0; it < 11; ++it) {
        int idx = tid + it * 256;
        if (idx < ACHUNKS) {
            int row = idx / (SCOLS * 8);
            int rem = idx - row * (SCOLS * 8);
            int col = rem >> 3, ch = rem & 7;
            uint4 v = *reinterpret_cast<const uint4*>(
                imgRow + (size_t)row * PW64 + (size_t)(w0 + col) * 64 + ch * 8);
            int byt = row * ASTR + ((col * 128 + ch * 16) ^ ((col & 7) << 4));
            *reinterpret_cast<uint4*>(smem + byt) = v;
        }
    }
}

// ---------------- router (+bsum, +tuple-tail zero); pooled holds SUMS ----------
__global__ __launch_bounds__(64) void router_kernel(const float* __restrict__ pooled,
                                                    const float* __restrict__ rw,
                                                    const float* __restrict__ rb,
                                                    const float* __restrict__ eb,
                                                    const float* __restrict__ b2,
                                                    int* __restrict__ topi,
                                                    float* __restrict__ topw,
                                                    float* __restrict__ bsum,
                                                    float* __restrict__ outz) {
    __shared__ int sti[16];
    __shared__ float stw[16];
    int b = threadIdx.x;
    if (b == 8) outz[(size_t)8 * 64 * HWSZ] = 0.f;  // tuple's scalar 0
    if (b < 8) {
        float lg[6];
        for (int e = 0; e < 6; ++e) {
            float s = 0.f;
            for (int c = 0; c < 64; ++c) s += pooled[b * 64 + c] * rw[e * 64 + c];
            s = s * (1.0f / (float)HWSZ) + rb[e];
            lg[e] = fminf(fmaxf(s, -10.f), 10.f) + eb[e];
        }
        float m = lg[0];
        for (int e = 1; e < 6; ++e) m = fmaxf(m, lg[e]);
        float den = 0.f, pr[6];
        for (int e = 0; e < 6; ++e) { pr[e] = expf(lg[e] - m); den += pr[e]; }
        float inv = 1.0f / den;
        for (int e = 0; e < 6; ++e) pr[e] = fminf(fmaxf(pr[e] * inv, 1e-6f), 1.0f);
        int i0 = 0; float v0 = pr[0];
        for (int e = 1; e < 6; ++e) if (pr[e] > v0) { v0 = pr[e]; i0 = e; }
        int i1 = -1; float v1 = -1.f;
        for (int e = 0; e < 6; ++e) { if (e == i0) continue; if (pr[e] > v1) { v1 = pr[e]; i1 = e; } }
        float s2 = v0 + v1 + 1e-8f;
        topi[b * 2 + 0] = i0; topi[b * 2 + 1] = i1;
        topw[b * 2 + 0] = v0 / s2; topw[b * 2 + 1] = v1 / s2;
        sti[b * 2 + 0] = i0; sti[b * 2 + 1] = i1;
        stw[b * 2 + 0] = v0 / s2; stw[b * 2 + 1] = v1 / s2;
    }
    __syncthreads();
    for (int i = threadIdx.x; i < 512; i += 64) {
        int bb = i >> 6, c = i & 63;
        bsum[i] = stw[bb * 2] * b2[sti[bb * 2] * 64 + c] +
                  stw[bb * 2 + 1] * b2[sti[bb * 2 + 1] * 64 + c];
    }
}

// ------------- x: NCHW fp32 -> padded NHWC bf16, fused global-avg-pool ---------
__global__ __launch_bounds__(256) void convx_kernel(const float* __restrict__ x,
                                                    ushort_t* __restrict__ xp,
                                                    float* __restrict__ pooled) {
    __shared__ ushort_t lt[128][72];
    int b = blockIdx.x >> 7, h = blockIdx.x & 127;
    int tid = threadIdx.x;
#pragma unroll
    for (int k = 0; k < 8; ++k) {
        int idx = tid + k * 256;            // 0..2047
        int ci = idx >> 5, wg = idx & 31;
        float4 v = *reinterpret_cast<const float4*>(
            x + ((size_t)b * 64 + ci) * HWSZ + (size_t)h * WW + wg * 4);
        lt[wg * 4 + 0][ci] = f2b(v.x);
        lt[wg * 4 + 1][ci] = f2b(v.y);
        lt[wg * 4 + 2][ci] = f2b(v.z);
        lt[wg * 4 + 3][ci] = f2b(v.w);
        float s4 = (v.x + v.y) + (v.z + v.w);
#pragma unroll
        for (int m = 16; m > 0; m >>= 1) s4 += __shfl_xor(s4, m, 64);
        if ((tid & 31) == 0) atomicAdd(pooled + b * 64 + ci, s4);
    }
    __syncthreads();
    int w = tid >> 1, half = tid & 1;
    const int4* src = reinterpret_cast<const int4*>(&lt[w][half * 32]);
    int4 a0 = src[0], a1 = src[1], a2 = src[2], a3 = src[3];
    int4* dst = reinterpret_cast<int4*>(
        xp + (((size_t)b * PW + (h + 1)) * PW + (w + 1)) * 64 + half * 32);
    dst[0] = a0; dst[1] = a1; dst[2] = a2; dst[3] = a3;
}

// ------------- w1 -> fragment-linear bf16: [e][t][kc][n][lane][8] -------------
__global__ __launch_bounds__(256) void convw1_kernel(const float* __restrict__ w1,
                                                     ushort_t* __restrict__ wb1f) {
    int blk = blockIdx.x;          // e*9+t, 54 blocks
    int e = blk / 9, t = blk - e * 9;
    for (int idx = threadIdx.x; idx < 4096; idx += 256) {
        int kc = idx >> 10, n = (idx >> 9) & 1, l = (idx >> 3) & 63, j = idx & 7;
        int co = n * 32 + (l & 31);
        int ci = kc * 16 + (l >> 5) * 8 + j;
        wb1f[(size_t)e * WBEXP + t * 4096 + idx] =
            f2b(w1[(((size_t)e * 64 + co) * 64 + ci) * 9 + t]);
    }
}

// ------------- w2 -> cw-scaled fragment-linear bf16: [bs][t][kc][n][lane][8] ----
__global__ __launch_bounds__(256) void convw2_kernel(const float* __restrict__ w2,
                                                     const int* __restrict__ topi,
                                                     const float* __restrict__ topw,
                                                     ushort_t* __restrict__ wb2f) {
    int blk = blockIdx.x;          // bs*9+t, 144 blocks
    int bs = blk / 9, t = blk - bs * 9;
    int e = topi[bs];
    float cw = topw[bs];
    for (int idx = threadIdx.x; idx < 4096; idx += 256) {
        int kc = idx >> 10, n = (idx >> 9) & 1, l = (idx >> 3) & 63, j = idx & 7;
        int co = n * 32 + (l & 31);
        int ci = kc * 16 + (l >> 5) * 8 + j;
        wb2f[(size_t)bs * WBEXP + t * 4096 + idx] =
            f2b(cw * w2[(((size_t)e * 64 + co) * 64 + ci) * 9 + t]);
    }
}

// ------------- zero halos: images 0..7 = xp, 8.. = hp -------------
__global__ __launch_bounds__(256) void halo_kernel(ushort_t* __restrict__ xp,
                                                   ushort_t* __restrict__ hp) {
    int img = blockIdx.x;
    ushort_t* p = (img < 8) ? (xp + (size_t)img * IMGSZ) : (hp + (size_t)(img - 8) * IMGSZ);
    int tid = threadIdx.x;
    int4 z = make_int4(0, 0, 0, 0);
    for (int i = tid; i < 1040; i += 256) {
        reinterpret_cast<int4*>(p)[i] = z;
        reinterpret_cast<int4*>(p + (size_t)129 * PW64)[i] = z;
    }
    for (int i = tid; i < 128 * 8; i += 256) {
        int row = 1 + (i >> 3), j = i & 7;
        reinterpret_cast<int4*>(p + (size_t)row * PW64)[j] = z;
        reinterpret_cast<int4*>(p + ((size_t)row * PW + 129) * 64)[j] = z;
    }
}

// ------------- conv1: xp -> gelu(conv+b1) -> hp  (LDS-tiled) -------------------
__global__ __launch_bounds__(256) void conv1_mfma(const ushort_t* __restrict__ xp,
                                                  const ushort_t* __restrict__ wb1f,
                                                  const float* __restrict__ b1,
                                                  const int* __restrict__ topi,
                                                  ushort_t* __restrict__ hp,
                                                  int nslots, int slot0) {
    __shared__ uint4 smem4[ACHUNKS];
    char* smem = (char*)smem4;
    const int z = blockIdx.z;
    const int b = z / nslots, sl = z - b * nslots, s = slot0 + sl;
    const int e = topi[b * 2 + s];
    const int tid = threadIdx.x, l = tid & 63, wid = tid >> 6;
    const int l31 = l & 31, lh = l >> 5;
    const int ht = blockIdx.x >> 2, wt = blockIdx.x & 3;
    const int h0 = ht * TR, w0 = wt * 32;
    const int r0 = wid * 2;   // wave's first output row within tile

    stage_tile(xp + (size_t)b * IMGSZ + (size_t)h0 * PW64, smem, w0, tid);
    __syncthreads();

    const ushort_t* wB = wb1f + (size_t)e * WBEXP + l * 8;
    f32x16 acc00, acc01, acc10, acc11;
#pragma unroll
    for (int k2 = 0; k2 < 16; ++k2) { acc00[k2] = 0.f; acc01[k2] = 0.f; acc10[k2] = 0.f; acc11[k2] = 0.f; }

#pragma unroll
    for (int dr = 0; dr < 3; ++dr) {
#pragma unroll
        for (int dc = 0; dc < 3; ++dc) {
            const int t = dr * 3 + dc;
            const int col = dc + l31;
            const int swz = (col & 7) << 4;
#pragma unroll
            for (int kc = 0; kc < 4; ++kc) {
                const int cb = (col * 128 + kc * 32 + lh * 16) ^ swz;
                sh8 a0 = *reinterpret_cast<const sh8*>(smem + (r0 + dr) * ASTR + cb);
                sh8 a1 = *reinterpret_cast<const sh8*>(smem + (r0 + dr + 1) * ASTR + cb);
                sh8 b0 = *reinterpret_cast<const sh8*>(wB + (t * 4 + kc) * 1024);
                sh8 b1 = *reinterpret_cast<const sh8*>(wB + (t * 4 + kc) * 1024 + 512);
                acc00 = mfma_bf16(a0, b0, acc00);
                acc01 = mfma_bf16(a0, b1, acc01);
                acc10 = mfma_bf16(a1, b0, acc10);
                acc11 = mfma_bf16(a1, b1, acc11);
            }
        }
    }

    const float bv0 = b1[e * 64 + l31];
    const float bv1 = b1[e * 64 + 32 + l31];
    const size_t base =
        (((size_t)(sl * 8 + b) * PW + (h0 + r0 + 1)) * PW + (w0 + 1)) * 64 + l31;
#pragma unroll
    for (int i = 0; i < 2; ++i) {
#pragma unroll
        for (int n = 0; n < 2; ++n) {
            f32x16 a = (i == 0) ? (n == 0 ? acc00 : acc01) : (n == 0 ? acc10 : acc11);
            const float bv = n ? bv1 : bv0;
            const size_t ob = base + (size_t)i * PW64 + n * 32;
#pragma unroll
            for (int r = 0; r < 16; ++r) {
                int px = (r & 3) + 8 * (r >> 2) + 4 * lh;
                hp[ob + (size_t)px * 64] = f2b(gelu_tanh(a[r] + bv));
            }
        }
    }
}

// ------------- conv2: hp(NS slots) -> sum conv (+bsum) -> out NCHW fp32 --------
template <int NS>
__global__ __launch_bounds__(256) void conv2_mfma(const ushort_t* __restrict__ hp,
                                                  const ushort_t* __restrict__ wb2f,
                                                  const float* __restrict__ bsum,
                                                  float* __restrict__ outF,
                                                  int s0, int addmode) {
    __shared__ uint4 smem4[ACHUNKS];
    char* smem = (char*)smem4;
    const int b = blockIdx.z;
    const int tid = threadIdx.x, l = tid & 63, wid = tid >> 6;
    const int l31 = l & 31, lh = l >> 5;
    const int ht = blockIdx.x >> 2, wt = blockIdx.x & 3;
    const int h0 = ht * TR, w0 = wt * 32;
    const int r0 = wid * 2;

    f32x16 acc00, acc01, acc10, acc11;
#pragma unroll
    for (int k2 = 0; k2 < 16; ++k2) { acc00[k2] = 0.f; acc01[k2] = 0.f; acc10[k2] = 0.f; acc11[k2] = 0.f; }

    for (int si = 0; si < NS; ++si) {
        __syncthreads();   // protect LDS from overwrite while other waves read
        stage_tile(hp + (size_t)(si * 8 + b) * IMGSZ + (size_t)h0 * PW64, smem, w0, tid);
        __syncthreads();

        const ushort_t* wB = wb2f + (size_t)(b * 2 + s0 + si) * WBEXP + l * 8;
#pragma unroll
        for (int dr = 0; dr < 3; ++dr) {
#pragma unroll
            for (int dc = 0; dc < 3; ++dc) {
                const int t = dr * 3 + dc;
                const int col = dc + l31;
                const int swz = (col & 7) << 4;
#pragma unroll
                for (int kc = 0; kc < 4; ++kc) {
                    const int cb = (col * 128 + kc * 32 + lh * 16) ^ swz;
                    sh8 a0 = *reinterpret_cast<const sh8*>(smem + (r0 + dr) * ASTR + cb);
                    sh8 a1 = *reinterpret_cast<const sh8*>(smem + (r0 + dr + 1) * ASTR + cb);
                    sh8 b0 = *reinterpret_cast<const sh8*>(wB + (t * 4 + kc) * 1024);
                    sh8 b1 = *reinterpret_cast<const sh8*>(wB + (t * 4 + kc) * 1024 + 512);
                    acc00 = mfma_bf16(a0, b0, acc00);
                    acc01 = mfma_bf16(a0, b1, acc01);
                    acc10 = mfma_bf16(a1, b0, acc10);
                    acc11 = mfma_bf16(a1, b1, acc11);
                }
            }
        }
    }

    __syncthreads();   // A-tile dead; reuse LDS for output transpose
    float* lt = (float*)smem4;   // per-wave slab [32][33] at wid*1056
    const float bq0 = addmode ? 0.f : bsum[b * 64 + l31];
    const float bq1 = addmode ? 0.f : bsum[b * 64 + 32 + l31];
#pragma unroll
    for (int i = 0; i < 2; ++i) {
        const int h = h0 + r0 + i;
#pragma unroll
        for (int n = 0; n < 2; ++n) {
            f32x16 a = (i == 0) ? (n == 0 ? acc00 : acc01) : (n == 0 ? acc10 : acc11);
            const float bq = n ? bq1 : bq0;
#pragma unroll
            for (int r = 0; r < 16; ++r) {
                int px = (r & 3) + 8 * (r >> 2) + 4 * lh;
                lt[wid * 1056 + px * 33 + l31] = a[r] + bq;
            }
            const int q = lh, co = l31;
            const size_t ob = ((size_t)(b * 64 + n * 32 + co)) * HWSZ +
                              (size_t)h * WW + w0 + q * 16;
#pragma unroll
            for (int v = 0; v < 4; ++v) {
                float o0 = lt[wid * 1056 + (q * 16 + v * 4 + 0) * 33 + co];
                float o1 = lt[wid * 1056 + (q * 16 + v * 4 + 1) * 33 + co];
                float o2 = lt[wid * 1056 + (q * 16 + v * 4 + 2) * 33 + co];
                float o3 = lt[wid * 1056 + (q * 16 + v * 4 + 3) * 33 + co];
                float4* dst = reinterpret_cast<float4*>(outF + ob + v * 4);
                if (addmode) {
                    float4 pv = *dst;
                    o0 += pv.x; o1 += pv.y; o2 += pv.z; o3 += pv.w;
                }
                float4 o; o.x = o0; o.y = o1; o.z = o2; o.w = o3;
                *dst = o;
            }
        }
    }
}

extern "C" void kernel_launch(void* const* d_in, const int* in_sizes, int n_in,
                              void* d_out, int out_size, void* d_ws, size_t ws_size,
                              hipStream_t stream) {
    const float* x  = (const float*)d_in[0];
    const float* rw = (const float*)d_in[1];
    const float* rb = (const float*)d_in[2];
    const float* eb = (const float*)d_in[3];
    const float* w1 = (const float*)d_in[4];
    const float* b1 = (const float*)d_in[5];
    const float* w2 = (const float*)d_in[6];
    const float* b2 = (const float*)d_in[7];
    float* out = (float*)d_out;

    char* ws = (char*)d_ws;
    float*    pooled = (float*)(ws + 0);
    int*      topi   = (int*)(ws + 2048);
    float*    topw   = (float*)(ws + 2112);
    float*    bsum   = (float*)(ws + 2176);
    ushort_t* wb1f   = (ushort_t*)(ws + 4352);
    ushort_t* wb2f   = (ushort_t*)(ws + 446720);
    ushort_t* xp     = (ushort_t*)(ws + 1626368);
    ushort_t* hp     = (ushort_t*)(ws + 18931968);

    const bool two = ws_size >= 53543168ull;  // hp holds both slots?

    hipMemsetAsync(pooled, 0, 512 * sizeof(float), stream);
    hipLaunchKernelGGL(convx_kernel, dim3(1024), dim3(256), 0, stream, x, xp, pooled);
    hipLaunchKernelGGL(router_kernel, dim3(1), dim3(64), 0, stream,
                       pooled, rw, rb, eb, b2, topi, topw, bsum, out);
    hipLaunchKernelGGL(convw1_kernel, dim3(54), dim3(256), 0, stream, w1, wb1f);
    hipLaunchKernelGGL(convw2_kernel, dim3(144), dim3(256), 0, stream, w2, topi, topw, wb2f);
    hipLaunchKernelGGL(halo_kernel, dim3(two ? 24 : 16), dim3(256), 0, stream, xp, hp);

    if (two) {
        hipLaunchKernelGGL(conv1_mfma, dim3(64, 1, 16), dim3(256), 0, stream,
                           xp, wb1f, b1, topi, hp, 2, 0);
        hipLaunchKernelGGL((conv2_mfma<2>), dim3(64, 1, 8), dim3(256), 0, stream,
                           hp, wb2f, bsum, out, 0, 0);
    } else {
        hipLaunchKernelGGL(conv1_mfma, dim3(64, 1, 8), dim3(256), 0, stream,
                           xp, wb1f, b1, topi, hp, 1, 0);
        hipLaunchKernelGGL((conv2_mfma<1>), dim3(64, 1, 8), dim3(256), 0, stream,
                           hp, wb2f, bsum, out, 0, 0);
        hipLaunchKernelGGL(conv1_mfma, dim3(64, 1, 8), dim3(256), 0, stream,
                           xp, wb1f, b1, topi, hp, 1, 1);
        hipLaunchKernelGGL((conv2_mfma<1>), dim3(64, 1, 8), dim3(256), 0, stream,
                           hp, wb2f, bsum, out, 1, 1);
    }
}

// Round 6
// 213.568 us; speedup vs baseline: 1.2850x; 1.1786x over previous
//
#include <hip/hip_runtime.h>
#include <hip/hip_bf16.h>
#include <cstdint>

typedef __attribute__((ext_vector_type(8))) short sh8;
typedef __attribute__((ext_vector_type(16))) float f32x16;
typedef unsigned short ushort_t;

#define HH 128
#define WW 128
#define HWSZ (HH*WW)
#define PW 130
#define PW64 (PW*64)
#define IMGSZ ((size_t)PW*PW*64)   // padded NHWC image, elements
#define WBEXP 36864                // elems per packed weight set: 9*4*2*512

#define SCOLS 34
#define ROWB (SCOLS*128)           // 4352 B per staged row (linear LDS)
#define TR1 8
#define SR1 10
#define CH1 (SR1*SCOLS*8)          // 2720 chunks (16 B each)
#define TR2 4
#define SR2 6
#define CH2 (SR2*SCOLS*8)          // 1632 chunks

typedef __attribute__((address_space(1))) const void gvoid_t;
typedef __attribute__((address_space(3))) void lvoid_t;

__device__ __forceinline__ float gelu_tanh(float x) {
    float u = 0.7978845608028654f * (x + 0.044715f * x * x * x);
    return 0.5f * x * (1.0f + tanhf(u));
}
__device__ __forceinline__ ushort_t f2b(float f) {
    __hip_bfloat16 h = __float2bfloat16(f);
    return *reinterpret_cast<ushort_t*>(&h);
}
__device__ __forceinline__ unsigned pack2(float a, float b) {
    return (unsigned)f2b(a) | ((unsigned)f2b(b) << 16);
}
__device__ __forceinline__ f32x16 mfma_bf16(sh8 a, sh8 b, f32x16 c) {
    return __builtin_amdgcn_mfma_f32_32x32x16_bf16(a, b, c, 0, 0, 0);
}

// stage rows h0..h0+SR-1, cols w0..w0+33 into LINEAR LDS via global_load_lds.
// swizzle moved to the SOURCE: chunk ch' = ch ^ (col&7)  (m173 pattern).
template <int NCH>
__device__ __forceinline__ void stage_gll(const ushort_t* __restrict__ imgRow,
                                          char* smem, int w0, int tid) {
#pragma unroll
    for (int it = 0; it < (NCH + 255) / 256; ++it) {
        int idx = tid + it * 256;
        if ((NCH & 255) == 0 || idx < NCH) {
            int row = idx / (SCOLS * 8);
            int rem = idx - row * (SCOLS * 8);
            int col = rem >> 3;
            int ch  = (rem & 7) ^ (col & 7);
            const ushort_t* src = imgRow + (size_t)row * PW64 + (size_t)(w0 + col) * 64 + ch * 8;
            __builtin_amdgcn_global_load_lds((gvoid_t*)src, (lvoid_t*)(smem + idx * 16),
                                             16, 0, 0);
        }
    }
}

// ---------------- router (+bsum, +tuple-tail zero); pooled holds SUMS ----------
__global__ __launch_bounds__(64) void router_kernel(const float* __restrict__ pooled,
                                                    const float* __restrict__ rw,
                                                    const float* __restrict__ rb,
                                                    const float* __restrict__ eb,
                                                    const float* __restrict__ b2,
                                                    int* __restrict__ topi,
                                                    float* __restrict__ topw,
                                                    float* __restrict__ bsum,
                                                    float* __restrict__ outz) {
    __shared__ int sti[16];
    __shared__ float stw[16];
    int b = threadIdx.x;
    if (b == 8) outz[(size_t)8 * 64 * HWSZ] = 0.f;  // tuple's scalar 0
    if (b < 8) {
        float lg[6];
        for (int e = 0; e < 6; ++e) {
            float s = 0.f;
            for (int c = 0; c < 64; ++c) s += pooled[b * 64 + c] * rw[e * 64 + c];
            s = s * (1.0f / (float)HWSZ) + rb[e];
            lg[e] = fminf(fmaxf(s, -10.f), 10.f) + eb[e];
        }
        float m = lg[0];
        for (int e = 1; e < 6; ++e) m = fmaxf(m, lg[e]);
        float den = 0.f, pr[6];
        for (int e = 0; e < 6; ++e) { pr[e] = expf(lg[e] - m); den += pr[e]; }
        float inv = 1.0f / den;
        for (int e = 0; e < 6; ++e) pr[e] = fminf(fmaxf(pr[e] * inv, 1e-6f), 1.0f);
        int i0 = 0; float v0 = pr[0];
        for (int e = 1; e < 6; ++e) if (pr[e] > v0) { v0 = pr[e]; i0 = e; }
        int i1 = -1; float v1 = -1.f;
        for (int e = 0; e < 6; ++e) { if (e == i0) continue; if (pr[e] > v1) { v1 = pr[e]; i1 = e; } }
        float s2 = v0 + v1 + 1e-8f;
        topi[b * 2 + 0] = i0; topi[b * 2 + 1] = i1;
        topw[b * 2 + 0] = v0 / s2; topw[b * 2 + 1] = v1 / s2;
        sti[b * 2 + 0] = i0; sti[b * 2 + 1] = i1;
        stw[b * 2 + 0] = v0 / s2; stw[b * 2 + 1] = v1 / s2;
    }
    __syncthreads();
    for (int i = threadIdx.x; i < 512; i += 64) {
        int bb = i >> 6, c = i & 63;
        bsum[i] = stw[bb * 2] * b2[sti[bb * 2] * 64 + c] +
                  stw[bb * 2 + 1] * b2[sti[bb * 2 + 1] * 64 + c];
    }
}

// ------------- x: NCHW fp32 -> padded NHWC bf16, fused global-avg-pool ---------
__global__ __launch_bounds__(256) void convx_kernel(const float* __restrict__ x,
                                                    ushort_t* __restrict__ xp,
                                                    float* __restrict__ pooled) {
    __shared__ ushort_t lt[128][72];
    int b = blockIdx.x >> 7, h = blockIdx.x & 127;
    int tid = threadIdx.x;
#pragma unroll
    for (int k = 0; k < 8; ++k) {
        int idx = tid + k * 256;            // 0..2047
        int ci = idx >> 5, wg = idx & 31;
        float4 v = *reinterpret_cast<const float4*>(
            x + ((size_t)b * 64 + ci) * HWSZ + (size_t)h * WW + wg * 4);
        lt[wg * 4 + 0][ci] = f2b(v.x);
        lt[wg * 4 + 1][ci] = f2b(v.y);
        lt[wg * 4 + 2][ci] = f2b(v.z);
        lt[wg * 4 + 3][ci] = f2b(v.w);
        float s4 = (v.x + v.y) + (v.z + v.w);
#pragma unroll
        for (int m = 16; m > 0; m >>= 1) s4 += __shfl_xor(s4, m, 64);
        if ((tid & 31) == 0) atomicAdd(pooled + b * 64 + ci, s4);
    }
    __syncthreads();
    int w = tid >> 1, half = tid & 1;
    const int4* src = reinterpret_cast<const int4*>(&lt[w][half * 32]);
    int4 a0 = src[0], a1 = src[1], a2 = src[2], a3 = src[3];
    int4* dst = reinterpret_cast<int4*>(
        xp + (((size_t)b * PW + (h + 1)) * PW + (w + 1)) * 64 + half * 32);
    dst[0] = a0; dst[1] = a1; dst[2] = a2; dst[3] = a3;
}

// ------------- prep: pack w1, pack w2 (cw-scaled), zero halos -------------------
__global__ __launch_bounds__(256) void prep_kernel(const float* __restrict__ w1,
                                                   const float* __restrict__ w2,
                                                   const int* __restrict__ topi,
                                                   const float* __restrict__ topw,
                                                   ushort_t* __restrict__ wb1f,
                                                   ushort_t* __restrict__ wb2f,
                                                   ushort_t* __restrict__ xp,
                                                   ushort_t* __restrict__ hp) {
    int blk = blockIdx.x;
    int tid = threadIdx.x;
    if (blk < 54) {               // w1 -> [e][t][kc][n][lane][8]
        int e = blk / 9, t = blk - e * 9;
        for (int idx = tid; idx < 4096; idx += 256) {
            int kc = idx >> 10, n = (idx >> 9) & 1, l = (idx >> 3) & 63, j = idx & 7;
            int co = n * 32 + (l & 31);
            int ci = kc * 16 + (l >> 5) * 8 + j;
            wb1f[(size_t)e * WBEXP + t * 4096 + idx] =
                f2b(w1[(((size_t)e * 64 + co) * 64 + ci) * 9 + t]);
        }
    } else if (blk < 198) {       // w2 -> cw-scaled [bs][t][kc][n][lane][8]
        int q = blk - 54;
        int bs = q / 9, t = q - bs * 9;
        int e = topi[bs];
        float cw = topw[bs];
        for (int idx = tid; idx < 4096; idx += 256) {
            int kc = idx >> 10, n = (idx >> 9) & 1, l = (idx >> 3) & 63, j = idx & 7;
            int co = n * 32 + (l & 31);
            int ci = kc * 16 + (l >> 5) * 8 + j;
            wb2f[(size_t)bs * WBEXP + t * 4096 + idx] =
                f2b(cw * w2[(((size_t)e * 64 + co) * 64 + ci) * 9 + t]);
        }
    } else {                      // halos
        int img = blk - 198;
        ushort_t* p = (img < 8) ? (xp + (size_t)img * IMGSZ)
                                : (hp + (size_t)(img - 8) * IMGSZ);
        int4 z = make_int4(0, 0, 0, 0);
        for (int i = tid; i < 1040; i += 256) {
            reinterpret_cast<int4*>(p)[i] = z;
            reinterpret_cast<int4*>(p + (size_t)129 * PW64)[i] = z;
        }
        for (int i = tid; i < 128 * 8; i += 256) {
            int row = 1 + (i >> 3), j = i & 7;
            reinterpret_cast<int4*>(p + (size_t)row * PW64)[j] = z;
            reinterpret_cast<int4*>(p + ((size_t)row * PW + 129) * 64)[j] = z;
        }
    }
}

// one (dr,dc)-batch K-phase for a 1-row wave: 8 weight loads, then 4 ds_read + 8 MFMA
__device__ __forceinline__ void conv_phase1(const char* sm, const ushort_t* wt_,
                                            int row, int l31, int lh,
                                            f32x16& acc0, f32x16& acc1, int dc) {
    sh8 wf[8];
#pragma unroll
    for (int kc = 0; kc < 4; ++kc) {
        wf[kc * 2]     = *reinterpret_cast<const sh8*>(wt_ + kc * 1024);
        wf[kc * 2 + 1] = *reinterpret_cast<const sh8*>(wt_ + kc * 1024 + 512);
    }
    __builtin_amdgcn_sched_barrier(0);
    const int colb = (dc + l31) * 128;
    const int swz = ((dc + l31) & 7) << 4;
#pragma unroll
    for (int kc = 0; kc < 4; ++kc) {
        sh8 a = *reinterpret_cast<const sh8*>(sm + row * ROWB + ((colb + (kc * 2 + lh) * 16) ^ swz));
        acc0 = mfma_bf16(wf[kc * 2], a, acc0);
        acc1 = mfma_bf16(wf[kc * 2 + 1], a, acc1);
    }
}

// ------------- conv1: xp -> gelu(conv+b1) -> hp  (8-row tile, gll-staged) -------
__global__ __launch_bounds__(256) void conv1_mfma(const ushort_t* __restrict__ xp,
                                                  const ushort_t* __restrict__ wb1f,
                                                  const float* __restrict__ b1,
                                                  const int* __restrict__ topi,
                                                  ushort_t* __restrict__ hp,
                                                  int nslots, int slot0) {
    __shared__ char smem[CH1 * 16];
    const int z = blockIdx.z;
    const int b = z / nslots, sl = z - b * nslots, s = slot0 + sl;
    const int e = topi[b * 2 + s];
    const int tid = threadIdx.x, l = tid & 63, wid = tid >> 6;
    const int l31 = l & 31, lh = l >> 5;
    const int ht = blockIdx.x >> 2, wt = blockIdx.x & 3;
    const int h0 = ht * TR1, w0 = wt * 32;
    const int r0 = wid * 2;   // 2 output rows per wave

    stage_gll<CH1>(xp + (size_t)b * IMGSZ + (size_t)h0 * PW64, smem, w0, tid);

    const ushort_t* wB = wb1f + (size_t)e * WBEXP + l * 8;
    f32x16 acc00, acc01, acc10, acc11;
#pragma unroll
    for (int k2 = 0; k2 < 16; ++k2) { acc00[k2] = 0.f; acc01[k2] = 0.f; acc10[k2] = 0.f; acc11[k2] = 0.f; }
    __syncthreads();   // implicit vmcnt(0) drain -> tile ready

#pragma unroll
    for (int dr = 0; dr < 3; ++dr) {
#pragma unroll
        for (int dc = 0; dc < 3; ++dc) {
            const ushort_t* wt_ = wB + (dr * 3 + dc) * 4096;
            sh8 wf[8];
#pragma unroll
            for (int kc = 0; kc < 4; ++kc) {
                wf[kc * 2]     = *reinterpret_cast<const sh8*>(wt_ + kc * 1024);
                wf[kc * 2 + 1] = *reinterpret_cast<const sh8*>(wt_ + kc * 1024 + 512);
            }
            __builtin_amdgcn_sched_barrier(0);
            const int colb = (dc + l31) * 128;
            const int swz = ((dc + l31) & 7) << 4;
#pragma unroll
            for (int kc = 0; kc < 4; ++kc) {
                const int cb = (colb + (kc * 2 + lh) * 16) ^ swz;
                sh8 a0 = *reinterpret_cast<const sh8*>(smem + (r0 + dr) * ROWB + cb);
                sh8 a1 = *reinterpret_cast<const sh8*>(smem + (r0 + dr + 1) * ROWB + cb);
                acc00 = mfma_bf16(wf[kc * 2], a0, acc00);
                acc01 = mfma_bf16(wf[kc * 2 + 1], a0, acc01);
                acc10 = mfma_bf16(wf[kc * 2], a1, acc10);
                acc11 = mfma_bf16(wf[kc * 2 + 1], a1, acc11);
            }
        }
    }

    // epilogue: lane = pixel (swapped operands); contiguous-ci 8B stores
    float4 bq[2][4];
#pragma unroll
    for (int n = 0; n < 2; ++n)
#pragma unroll
        for (int g = 0; g < 4; ++g)
            bq[n][g] = *reinterpret_cast<const float4*>(b1 + e * 64 + n * 32 + g * 8 + 4 * lh);
    const size_t pbase = (size_t)(sl * 8 + b) * IMGSZ +
                         (size_t)(h0 + r0 + 1) * PW64 + (size_t)(w0 + l31 + 1) * 64;
#pragma unroll
    for (int i = 0; i < 2; ++i) {
#pragma unroll
        for (int n = 0; n < 2; ++n) {
            f32x16 a = (i == 0) ? (n == 0 ? acc00 : acc01) : (n == 0 ? acc10 : acc11);
#pragma unroll
            for (int g = 0; g < 4; ++g) {
                float v0 = gelu_tanh(a[g * 4 + 0] + bq[n][g].x);
                float v1 = gelu_tanh(a[g * 4 + 1] + bq[n][g].y);
                float v2 = gelu_tanh(a[g * 4 + 2] + bq[n][g].z);
                float v3 = gelu_tanh(a[g * 4 + 3] + bq[n][g].w);
                uint2 u; u.x = pack2(v0, v1); u.y = pack2(v2, v3);
                *reinterpret_cast<uint2*>(hp + pbase + (size_t)i * PW64 + n * 32 + g * 8 + 4 * lh) = u;
            }
        }
    }
}

// ------------- conv2: hp(NS slots) -> sum conv (+bsum) -> out NCHW fp32 --------
// 4-row tile, 1 row/wave, slot double-buffered gll staging
template <int NS>
__global__ __launch_bounds__(256) void conv2_mfma(const ushort_t* __restrict__ hp,
                                                  const ushort_t* __restrict__ wb2f,
                                                  const float* __restrict__ bsum,
                                                  float* __restrict__ outF,
                                                  int s0, int addmode) {
    __shared__ char smem[2][CH2 * 16];
    const int b = blockIdx.z;
    const int tid = threadIdx.x, l = tid & 63, wid = tid >> 6;
    const int l31 = l & 31, lh = l >> 5;
    const int ht = blockIdx.x >> 2, wt = blockIdx.x & 3;
    const int h0 = ht * TR2, w0 = wt * 32;
    const int row0 = wid;   // wave's output row within tile

    stage_gll<CH2>(hp + (size_t)b * IMGSZ + (size_t)h0 * PW64, smem[0], w0, tid);

    f32x16 acc0, acc1;
#pragma unroll
    for (int k2 = 0; k2 < 16; ++k2) { acc0[k2] = 0.f; acc1[k2] = 0.f; }
    __syncthreads();   // buf0 ready

    if (NS == 2)       // issue slot-1 stage; flies under slot-0 compute
        stage_gll<CH2>(hp + (size_t)(8 + b) * IMGSZ + (size_t)h0 * PW64, smem[1], w0, tid);

    {
        const ushort_t* wB = wb2f + (size_t)(b * 2 + s0) * WBEXP + l * 8;
#pragma unroll
        for (int dr = 0; dr < 3; ++dr)
#pragma unroll
            for (int dc = 0; dc < 3; ++dc)
                conv_phase1(smem[0], wB + (dr * 3 + dc) * 4096, row0 + dr, l31, lh, acc0, acc1, dc);
    }
    if (NS == 2) {
        __syncthreads();   // drains vmcnt -> buf1 ready
        const ushort_t* wB = wb2f + (size_t)(b * 2 + s0 + 1) * WBEXP + l * 8;
#pragma unroll
        for (int dr = 0; dr < 3; ++dr)
#pragma unroll
            for (int dc = 0; dc < 3; ++dc)
                conv_phase1(smem[1], wB + (dr * 3 + dc) * 4096, row0 + dr, l31, lh, acc0, acc1, dc);
    }

    __syncthreads();   // A-tiles dead; reuse buf0 for per-wave transpose slabs
    float* lt = reinterpret_cast<float*>(smem[0]) + wid * 1056;  // [32 px][33]
    float4 bq[2][4];
#pragma unroll
    for (int n = 0; n < 2; ++n)
#pragma unroll
        for (int g = 0; g < 4; ++g)
            bq[n][g] = addmode ? make_float4(0.f, 0.f, 0.f, 0.f)
                               : *reinterpret_cast<const float4*>(bsum + b * 64 + n * 32 + g * 8 + 4 * lh);
    const int h = h0 + row0;
#pragma unroll
    for (int n = 0; n < 2; ++n) {
        f32x16 a = n ? acc1 : acc0;
#pragma unroll
        for (int r = 0; r < 16; ++r) {
            int co = (r & 3) + 8 * (r >> 2) + 4 * lh;
            float bv = (r & 3) == 0 ? bq[n][r >> 2].x : (r & 3) == 1 ? bq[n][r >> 2].y
                     : (r & 3) == 2 ? bq[n][r >> 2].z : bq[n][r >> 2].w;
            lt[l31 * 33 + co] = a[r] + bv;     // lt[px][co]
        }
        const int q = lh, co = l31;
        const size_t ob = ((size_t)(b * 64 + n * 32 + co)) * HWSZ + (size_t)h * WW + w0 + q * 16;
#pragma unroll
        for (int v = 0; v < 4; ++v) {
            float o0 = lt[(q * 16 + v * 4 + 0) * 33 + co];
            float o1 = lt[(q * 16 + v * 4 + 1) * 33 + co];
            float o2 = lt[(q * 16 + v * 4 + 2) * 33 + co];
            float o3 = lt[(q * 16 + v * 4 + 3) * 33 + co];
            float4* dst = reinterpret_cast<float4*>(outF + ob + v * 4);
            if (addmode) {
                float4 pv = *dst;
                o0 += pv.x; o1 += pv.y; o2 += pv.z; o3 += pv.w;
            }
            float4 o; o.x = o0; o.y = o1; o.z = o2; o.w = o3;
            *dst = o;
        }
    }
}

extern "C" void kernel_launch(void* const* d_in, const int* in_sizes, int n_in,
                              void* d_out, int out_size, void* d_ws, size_t ws_size,
                              hipStream_t stream) {
    const float* x  = (const float*)d_in[0];
    const float* rw = (const float*)d_in[1];
    const float* rb = (const float*)d_in[2];
    const float* eb = (const float*)d_in[3];
    const float* w1 = (const float*)d_in[4];
    const float* b1 = (const float*)d_in[5];
    const float* w2 = (const float*)d_in[6];
    const float* b2 = (const float*)d_in[7];
    float* out = (float*)d_out;

    char* ws = (char*)d_ws;
    float*    pooled = (float*)(ws + 0);
    int*      topi   = (int*)(ws + 2048);
    float*    topw   = (float*)(ws + 2112);
    float*    bsum   = (float*)(ws + 2176);
    ushort_t* wb1f   = (ushort_t*)(ws + 4352);
    ushort_t* wb2f   = (ushort_t*)(ws + 446720);
    ushort_t* xp     = (ushort_t*)(ws + 1626368);
    ushort_t* hp     = (ushort_t*)(ws + 18931968);

    const bool two = ws_size >= 53543168ull;  // hp holds both slots?

    hipMemsetAsync(pooled, 0, 512 * sizeof(float), stream);
    hipLaunchKernelGGL(convx_kernel, dim3(1024), dim3(256), 0, stream, x, xp, pooled);
    hipLaunchKernelGGL(router_kernel, dim3(1), dim3(64), 0, stream,
                       pooled, rw, rb, eb, b2, topi, topw, bsum, out);
    hipLaunchKernelGGL(prep_kernel, dim3(198 + 8 + (two ? 16 : 8)), dim3(256), 0, stream,
                       w1, w2, topi, topw, wb1f, wb2f, xp, hp);

    if (two) {
        hipLaunchKernelGGL(conv1_mfma, dim3(64, 1, 16), dim3(256), 0, stream,
                           xp, wb1f, b1, topi, hp, 2, 0);
        hipLaunchKernelGGL((conv2_mfma<2>), dim3(128, 1, 8), dim3(256), 0, stream,
                           hp, wb2f, bsum, out, 0, 0);
    } else {
        hipLaunchKernelGGL(conv1_mfma, dim3(64, 1, 8), dim3(256), 0, stream,
                           xp, wb1f, b1, topi, hp, 1, 0);
        hipLaunchKernelGGL((conv2_mfma<1>), dim3(128, 1, 8), dim3(256), 0, stream,
                           hp, wb2f, bsum, out, 0, 0);
        hipLaunchKernelGGL(conv1_mfma, dim3(64, 1, 8), dim3(256), 0, stream,
                           xp, wb1f, b1, topi, hp, 1, 1);
        hipLaunchKernelGGL((conv2_mfma<1>), dim3(128, 1, 8), dim3(256), 0, stream,
                           hp, wb2f, bsum, out, 1, 1);
    }
}

// Round 7
// 211.165 us; speedup vs baseline: 1.2996x; 1.0114x over previous
//
#include <hip/hip_runtime.h>
#include <hip/hip_bf16.h>
#include <cstdint>

typedef __attribute__((ext_vector_type(8))) short sh8;
typedef __attribute__((ext_vector_type(16))) float f32x16;
typedef unsigned short ushort_t;

#define HH 128
#define WW 128
#define HWSZ (HH*WW)
#define PW 130
#define PW64 (PW*64)
#define IMGSZ ((size_t)PW*PW*64)   // padded NHWC image, elements
#define WBEXP 36864                // elems per packed weight set: 9*4*2*512

#define SCOLS 34
#define ROWB (SCOLS*128)           // 4352 B per staged row (linear LDS)
#define TRT 4                      // output rows per tile (both convs)
#define SRT 6                      // staged rows
#define CHT (SRT*SCOLS*8)          // 1632 chunks (16 B each)

typedef __attribute__((address_space(1))) const void gvoid_t;
typedef __attribute__((address_space(3))) void lvoid_t;

// fast tanh-GELU: x * sigmoid(2u), u = 0.79788456(x + 0.044715 x^3)
// exp2/rcp on the transcendental pipe; ~1e-4 rel err << bf16 quantization.
__device__ __forceinline__ float gelu_fast(float x) {
    float m = x * __builtin_fmaf(x * x, -0.10294323f, -2.30220805f);
    return x * __builtin_amdgcn_rcpf(1.0f + __builtin_amdgcn_exp2f(m));
}
__device__ __forceinline__ ushort_t f2b(float f) {
    __hip_bfloat16 h = __float2bfloat16(f);
    return *reinterpret_cast<ushort_t*>(&h);
}
__device__ __forceinline__ unsigned pack2(float a, float b) {
    return (unsigned)f2b(a) | ((unsigned)f2b(b) << 16);
}
__device__ __forceinline__ f32x16 mfma_bf16(sh8 a, sh8 b, f32x16 c) {
    return __builtin_amdgcn_mfma_f32_32x32x16_bf16(a, b, c, 0, 0, 0);
}

// stage rows h0..h0+SRT-1, cols w0..w0+33 into LINEAR LDS via global_load_lds.
// swizzle moved to the SOURCE: chunk ch' = ch ^ (col&7)  (m173 pattern).
__device__ __forceinline__ void stage_gll(const ushort_t* __restrict__ imgRow,
                                          char* smem, int w0, int tid) {
#pragma unroll
    for (int it = 0; it < 7; ++it) {
        int idx = tid + it * 256;
        if (idx < CHT) {
            int row = idx / (SCOLS * 8);
            int rem = idx - row * (SCOLS * 8);
            int col = rem >> 3;
            int ch  = (rem & 7) ^ (col & 7);
            const ushort_t* src = imgRow + (size_t)row * PW64 + (size_t)(w0 + col) * 64 + ch * 8;
            __builtin_amdgcn_global_load_lds((gvoid_t*)src, (lvoid_t*)(smem + idx * 16),
                                             16, 0, 0);
        }
    }
}

// one (dr,dc) K-phase for a 1-row wave: 8 weight loads batched, then 4 ds_read + 8 MFMA
__device__ __forceinline__ void conv_phase1(const char* sm, const ushort_t* wt_,
                                            int row, int l31, int lh,
                                            f32x16& acc0, f32x16& acc1, int dc) {
    sh8 wf[8];
#pragma unroll
    for (int kc = 0; kc < 4; ++kc) {
        wf[kc * 2]     = *reinterpret_cast<const sh8*>(wt_ + kc * 1024);
        wf[kc * 2 + 1] = *reinterpret_cast<const sh8*>(wt_ + kc * 1024 + 512);
    }
    __builtin_amdgcn_sched_barrier(0);
    const int colb = (dc + l31) * 128;
    const int swz = ((dc + l31) & 7) << 4;
#pragma unroll
    for (int kc = 0; kc < 4; ++kc) {
        sh8 a = *reinterpret_cast<const sh8*>(sm + row * ROWB + ((colb + (kc * 2 + lh) * 16) ^ swz));
        acc0 = mfma_bf16(wf[kc * 2], a, acc0);
        acc1 = mfma_bf16(wf[kc * 2 + 1], a, acc1);
    }
}

// ---------------- router (+bsum, +tuple-tail zero); pooled holds SUMS ----------
__global__ __launch_bounds__(64) void router_kernel(const float* __restrict__ pooled,
                                                    const float* __restrict__ rw,
                                                    const float* __restrict__ rb,
                                                    const float* __restrict__ eb,
                                                    const float* __restrict__ b2,
                                                    int* __restrict__ topi,
                                                    float* __restrict__ topw,
                                                    float* __restrict__ bsum,
                                                    float* __restrict__ outz) {
    __shared__ int sti[16];
    __shared__ float stw[16];
    int b = threadIdx.x;
    if (b == 8) outz[(size_t)8 * 64 * HWSZ] = 0.f;  // tuple's scalar 0
    if (b < 8) {
        float lg[6];
        for (int e = 0; e < 6; ++e) {
            float s = 0.f;
            for (int c = 0; c < 64; ++c) s += pooled[b * 64 + c] * rw[e * 64 + c];
            s = s * (1.0f / (float)HWSZ) + rb[e];
            lg[e] = fminf(fmaxf(s, -10.f), 10.f) + eb[e];
        }
        float m = lg[0];
        for (int e = 1; e < 6; ++e) m = fmaxf(m, lg[e]);
        float den = 0.f, pr[6];
        for (int e = 0; e < 6; ++e) { pr[e] = expf(lg[e] - m); den += pr[e]; }
        float inv = 1.0f / den;
        for (int e = 0; e < 6; ++e) pr[e] = fminf(fmaxf(pr[e] * inv, 1e-6f), 1.0f);
        int i0 = 0; float v0 = pr[0];
        for (int e = 1; e < 6; ++e) if (pr[e] > v0) { v0 = pr[e]; i0 = e; }
        int i1 = -1; float v1 = -1.f;
        for (int e = 0; e < 6; ++e) { if (e == i0) continue; if (pr[e] > v1) { v1 = pr[e]; i1 = e; } }
        float s2 = v0 + v1 + 1e-8f;
        topi[b * 2 + 0] = i0; topi[b * 2 + 1] = i1;
        topw[b * 2 + 0] = v0 / s2; topw[b * 2 + 1] = v1 / s2;
        sti[b * 2 + 0] = i0; sti[b * 2 + 1] = i1;
        stw[b * 2 + 0] = v0 / s2; stw[b * 2 + 1] = v1 / s2;
    }
    __syncthreads();
    for (int i = threadIdx.x; i < 512; i += 64) {
        int bb = i >> 6, c = i & 63;
        bsum[i] = stw[bb * 2] * b2[sti[bb * 2] * 64 + c] +
                  stw[bb * 2 + 1] * b2[sti[bb * 2 + 1] * 64 + c];
    }
}

// ------------- x: NCHW fp32 -> padded NHWC bf16, fused global-avg-pool ---------
__global__ __launch_bounds__(256) void convx_kernel(const float* __restrict__ x,
                                                    ushort_t* __restrict__ xp,
                                                    float* __restrict__ pooled) {
    __shared__ ushort_t lt[128][72];
    int b = blockIdx.x >> 7, h = blockIdx.x & 127;
    int tid = threadIdx.x;
#pragma unroll
    for (int k = 0; k < 8; ++k) {
        int idx = tid + k * 256;            // 0..2047
        int ci = idx >> 5, wg = idx & 31;
        float4 v = *reinterpret_cast<const float4*>(
            x + ((size_t)b * 64 + ci) * HWSZ + (size_t)h * WW + wg * 4);
        lt[wg * 4 + 0][ci] = f2b(v.x);
        lt[wg * 4 + 1][ci] = f2b(v.y);
        lt[wg * 4 + 2][ci] = f2b(v.z);
        lt[wg * 4 + 3][ci] = f2b(v.w);
        float s4 = (v.x + v.y) + (v.z + v.w);
#pragma unroll
        for (int m = 16; m > 0; m >>= 1) s4 += __shfl_xor(s4, m, 64);
        if ((tid & 31) == 0) atomicAdd(pooled + b * 64 + ci, s4);
    }
    __syncthreads();
    int w = tid >> 1, half = tid & 1;
    const int4* src = reinterpret_cast<const int4*>(&lt[w][half * 32]);
    int4 a0 = src[0], a1 = src[1], a2 = src[2], a3 = src[3];
    int4* dst = reinterpret_cast<int4*>(
        xp + (((size_t)b * PW + (h + 1)) * PW + (w + 1)) * 64 + half * 32);
    dst[0] = a0; dst[1] = a1; dst[2] = a2; dst[3] = a3;
}

// ------------- prep: pack w1, pack w2 (cw-scaled), zero halos -------------------
__global__ __launch_bounds__(256) void prep_kernel(const float* __restrict__ w1,
                                                   const float* __restrict__ w2,
                                                   const int* __restrict__ topi,
                                                   const float* __restrict__ topw,
                                                   ushort_t* __restrict__ wb1f,
                                                   ushort_t* __restrict__ wb2f,
                                                   ushort_t* __restrict__ xp,
                                                   ushort_t* __restrict__ hp) {
    int blk = blockIdx.x;
    int tid = threadIdx.x;
    if (blk < 54) {               // w1 -> [e][t][kc][n][lane][8]
        int e = blk / 9, t = blk - e * 9;
        for (int idx = tid; idx < 4096; idx += 256) {
            int kc = idx >> 10, n = (idx >> 9) & 1, l = (idx >> 3) & 63, j = idx & 7;
            int co = n * 32 + (l & 31);
            int ci = kc * 16 + (l >> 5) * 8 + j;
            wb1f[(size_t)e * WBEXP + t * 4096 + idx] =
                f2b(w1[(((size_t)e * 64 + co) * 64 + ci) * 9 + t]);
        }
    } else if (blk < 198) {       // w2 -> cw-scaled [bs][t][kc][n][lane][8]
        int q = blk - 54;
        int bs = q / 9, t = q - bs * 9;
        int e = topi[bs];
        float cw = topw[bs];
        for (int idx = tid; idx < 4096; idx += 256) {
            int kc = idx >> 10, n = (idx >> 9) & 1, l = (idx >> 3) & 63, j = idx & 7;
            int co = n * 32 + (l & 31);
            int ci = kc * 16 + (l >> 5) * 8 + j;
            wb2f[(size_t)bs * WBEXP + t * 4096 + idx] =
                f2b(cw * w2[(((size_t)e * 64 + co) * 64 + ci) * 9 + t]);
        }
    } else {                      // halos
        int img = blk - 198;
        ushort_t* p = (img < 8) ? (xp + (size_t)img * IMGSZ)
                                : (hp + (size_t)(img - 8) * IMGSZ);
        int4 z = make_int4(0, 0, 0, 0);
        for (int i = tid; i < 1040; i += 256) {
            reinterpret_cast<int4*>(p)[i] = z;
            reinterpret_cast<int4*>(p + (size_t)129 * PW64)[i] = z;
        }
        for (int i = tid; i < 128 * 8; i += 256) {
            int row = 1 + (i >> 3), j = i & 7;
            reinterpret_cast<int4*>(p + (size_t)row * PW64)[j] = z;
            reinterpret_cast<int4*>(p + ((size_t)row * PW + 129) * 64)[j] = z;
        }
    }
}

// ------------- conv1: xp -> gelu(conv+b1) -> hp  (4-row tile, 1 row/wave) ------
__global__ __launch_bounds__(256) void conv1_mfma(const ushort_t* __restrict__ xp,
                                                  const ushort_t* __restrict__ wb1f,
                                                  const float* __restrict__ b1,
                                                  const int* __restrict__ topi,
                                                  ushort_t* __restrict__ hp,
                                                  int nslots, int slot0) {
    __shared__ char smem[CHT * 16];
    const int z = blockIdx.z;
    const int b = z / nslots, sl = z - b * nslots, s = slot0 + sl;
    const int e = topi[b * 2 + s];
    const int tid = threadIdx.x, l = tid & 63, wid = tid >> 6;
    const int l31 = l & 31, lh = l >> 5;
    const int ht = blockIdx.x >> 2, wt = blockIdx.x & 3;
    const int h0 = ht * TRT, w0 = wt * 32;
    const int row0 = wid;

    stage_gll(xp + (size_t)b * IMGSZ + (size_t)h0 * PW64, smem, w0, tid);

    const ushort_t* wB = wb1f + (size_t)e * WBEXP + l * 8;
    f32x16 acc0, acc1;
#pragma unroll
    for (int k2 = 0; k2 < 16; ++k2) { acc0[k2] = 0.f; acc1[k2] = 0.f; }
    __syncthreads();   // implicit vmcnt(0) drain -> tile ready

#pragma unroll
    for (int dr = 0; dr < 3; ++dr)
#pragma unroll
        for (int dc = 0; dc < 3; ++dc)
            conv_phase1(smem, wB + (dr * 3 + dc) * 4096, row0 + dr, l31, lh, acc0, acc1, dc);

    // epilogue: lane = pixel; contiguous-ci 8B stores
    float4 bq[2][4];
#pragma unroll
    for (int n = 0; n < 2; ++n)
#pragma unroll
        for (int g = 0; g < 4; ++g)
            bq[n][g] = *reinterpret_cast<const float4*>(b1 + e * 64 + n * 32 + g * 8 + 4 * lh);
    const size_t pbase = (size_t)(sl * 8 + b) * IMGSZ +
                         (size_t)(h0 + row0 + 1) * PW64 + (size_t)(w0 + l31 + 1) * 64;
#pragma unroll
    for (int n = 0; n < 2; ++n) {
        f32x16 a = n ? acc1 : acc0;
#pragma unroll
        for (int g = 0; g < 4; ++g) {
            float v0 = gelu_fast(a[g * 4 + 0] + bq[n][g].x);
            float v1 = gelu_fast(a[g * 4 + 1] + bq[n][g].y);
            float v2 = gelu_fast(a[g * 4 + 2] + bq[n][g].z);
            float v3 = gelu_fast(a[g * 4 + 3] + bq[n][g].w);
            uint2 u; u.x = pack2(v0, v1); u.y = pack2(v2, v3);
            *reinterpret_cast<uint2*>(hp + pbase + n * 32 + g * 8 + 4 * lh) = u;
        }
    }
}

// ------------- conv2: hp(NS slots) -> sum conv (+bsum) -> out NCHW fp32 --------
// 4-row tile, 1 row/wave, slot double-buffered gll staging
template <int NS>
__global__ __launch_bounds__(256) void conv2_mfma(const ushort_t* __restrict__ hp,
                                                  const ushort_t* __restrict__ wb2f,
                                                  const float* __restrict__ bsum,
                                                  float* __restrict__ outF,
                                                  int s0, int addmode) {
    __shared__ char smem[2][CHT * 16];
    const int b = blockIdx.z;
    const int tid = threadIdx.x, l = tid & 63, wid = tid >> 6;
    const int l31 = l & 31, lh = l >> 5;
    const int ht = blockIdx.x >> 2, wt = blockIdx.x & 3;
    const int h0 = ht * TRT, w0 = wt * 32;
    const int row0 = wid;

    stage_gll(hp + (size_t)b * IMGSZ + (size_t)h0 * PW64, smem[0], w0, tid);

    f32x16 acc0, acc1;
#pragma unroll
    for (int k2 = 0; k2 < 16; ++k2) { acc0[k2] = 0.f; acc1[k2] = 0.f; }
    __syncthreads();   // buf0 ready

    if (NS == 2)       // issue slot-1 stage; flies under slot-0 compute
        stage_gll(hp + (size_t)(8 + b) * IMGSZ + (size_t)h0 * PW64, smem[1], w0, tid);

    {
        const ushort_t* wB = wb2f + (size_t)(b * 2 + s0) * WBEXP + l * 8;
#pragma unroll
        for (int dr = 0; dr < 3; ++dr)
#pragma unroll
            for (int dc = 0; dc < 3; ++dc)
                conv_phase1(smem[0], wB + (dr * 3 + dc) * 4096, row0 + dr, l31, lh, acc0, acc1, dc);
    }
    if (NS == 2) {
        __syncthreads();   // drains vmcnt -> buf1 ready
        const ushort_t* wB = wb2f + (size_t)(b * 2 + s0 + 1) * WBEXP + l * 8;
#pragma unroll
        for (int dr = 0; dr < 3; ++dr)
#pragma unroll
            for (int dc = 0; dc < 3; ++dc)
                conv_phase1(smem[1], wB + (dr * 3 + dc) * 4096, row0 + dr, l31, lh, acc0, acc1, dc);
    }

    __syncthreads();   // A-tiles dead; reuse buf0 for per-wave transpose slabs
    float* lt = reinterpret_cast<float*>(smem[0]) + wid * 1056;  // [32 px][33]
    float4 bq[2][4];
#pragma unroll
    for (int n = 0; n < 2; ++n)
#pragma unroll
        for (int g = 0; g < 4; ++g)
            bq[n][g] = addmode ? make_float4(0.f, 0.f, 0.f, 0.f)
                               : *reinterpret_cast<const float4*>(bsum + b * 64 + n * 32 + g * 8 + 4 * lh);
    const int h = h0 + row0;
#pragma unroll
    for (int n = 0; n < 2; ++n) {
        f32x16 a = n ? acc1 : acc0;
#pragma unroll
        for (int r = 0; r < 16; ++r) {
            int co = (r & 3) + 8 * (r >> 2) + 4 * lh;
            float bv = (r & 3) == 0 ? bq[n][r >> 2].x : (r & 3) == 1 ? bq[n][r >> 2].y
                     : (r & 3) == 2 ? bq[n][r >> 2].z : bq[n][r >> 2].w;
            lt[l31 * 33 + co] = a[r] + bv;     // lt[px][co]
        }
        const int q = lh, co = l31;
        const size_t ob = ((size_t)(b * 64 + n * 32 + co)) * HWSZ + (size_t)h * WW + w0 + q * 16;
#pragma unroll
        for (int v = 0; v < 4; ++v) {
            float o0 = lt[(q * 16 + v * 4 + 0) * 33 + co];
            float o1 = lt[(q * 16 + v * 4 + 1) * 33 + co];
            float o2 = lt[(q * 16 + v * 4 + 2) * 33 + co];
            float o3 = lt[(q * 16 + v * 4 + 3) * 33 + co];
            float4* dst = reinterpret_cast<float4*>(outF + ob + v * 4);
            if (addmode) {
                float4 pv = *dst;
                o0 += pv.x; o1 += pv.y; o2 += pv.z; o3 += pv.w;
            }
            float4 o; o.x = o0; o.y = o1; o.z = o2; o.w = o3;
            *dst = o;
        }
    }
}

extern "C" void kernel_launch(void* const* d_in, const int* in_sizes, int n_in,
                              void* d_out, int out_size, void* d_ws, size_t ws_size,
                              hipStream_t stream) {
    const float* x  = (const float*)d_in[0];
    const float* rw = (const float*)d_in[1];
    const float* rb = (const float*)d_in[2];
    const float* eb = (const float*)d_in[3];
    const float* w1 = (const float*)d_in[4];
    const float* b1 = (const float*)d_in[5];
    const float* w2 = (const float*)d_in[6];
    const float* b2 = (const float*)d_in[7];
    float* out = (float*)d_out;

    char* ws = (char*)d_ws;
    float*    pooled = (float*)(ws + 0);
    int*      topi   = (int*)(ws + 2048);
    float*    topw   = (float*)(ws + 2112);
    float*    bsum   = (float*)(ws + 2176);
    ushort_t* wb1f   = (ushort_t*)(ws + 4352);
    ushort_t* wb2f   = (ushort_t*)(ws + 446720);
    ushort_t* xp     = (ushort_t*)(ws + 1626368);
    ushort_t* hp     = (ushort_t*)(ws + 18931968);

    const bool two = ws_size >= 53543168ull;  // hp holds both slots?

    hipMemsetAsync(pooled, 0, 512 * sizeof(float), stream);
    hipLaunchKernelGGL(convx_kernel, dim3(1024), dim3(256), 0, stream, x, xp, pooled);
    hipLaunchKernelGGL(router_kernel, dim3(1), dim3(64), 0, stream,
                       pooled, rw, rb, eb, b2, topi, topw, bsum, out);
    hipLaunchKernelGGL(prep_kernel, dim3(198 + 8 + (two ? 16 : 8)), dim3(256), 0, stream,
                       w1, w2, topi, topw, wb1f, wb2f, xp, hp);

    if (two) {
        hipLaunchKernelGGL(conv1_mfma, dim3(128, 1, 16), dim3(256), 0, stream,
                           xp, wb1f, b1, topi, hp, 2, 0);
        hipLaunchKernelGGL((conv2_mfma<2>), dim3(128, 1, 8), dim3(256), 0, stream,
                           hp, wb2f, bsum, out, 0, 0);
    } else {
        hipLaunchKernelGGL(conv1_mfma, dim3(128, 1, 8), dim3(256), 0, stream,
                           xp, wb1f, b1, topi, hp, 1, 0);
        hipLaunchKernelGGL((conv2_mfma<1>), dim3(128, 1, 8), dim3(256), 0, stream,
                           hp, wb2f, bsum, out, 0, 0);
        hipLaunchKernelGGL(conv1_mfma, dim3(128, 1, 8), dim3(256), 0, stream,
                           xp, wb1f, b1, topi, hp, 1, 1);
        hipLaunchKernelGGL((conv2_mfma<1>), dim3(128, 1, 8), dim3(256), 0, stream,
                           hp, wb2f, bsum, out, 1, 1);
    }
}